// Round 2
// baseline (1339.838 us; speedup 1.0000x reference)
//
#include <hip/hip_runtime.h>

#define TPB 256
#define BKT_SHIFT 8
#define BKT_SZ 256
#define CHUNK 8192

// ---------------- phase 1: per-chunk bucket histogram ----------------
__global__ void k_count(const int* __restrict__ dst, int* __restrict__ counts,
                        int E, int NB, int NCHUNK) {
  __shared__ int hist[512];
  int t = threadIdx.x;
  for (int d = t; d < NB; d += TPB) hist[d] = 0;
  __syncthreads();
  int base = blockIdx.x * CHUNK;
  for (int i = t; i < CHUNK; i += TPB) {
    int e = base + i;
    if (e < E) atomicAdd(&hist[dst[e] >> BKT_SHIFT], 1);
  }
  __syncthreads();
  for (int d = t; d < NB; d += TPB)
    counts[d * NCHUNK + blockIdx.x] = hist[d];
}

// ---------------- global exclusive scan (single block, 1024 thr) -----
__global__ void k_scan(int* __restrict__ a, int total) {
  __shared__ int s[1024];
  int t = threadIdx.x;
  int seg = (total + 1023) >> 10;
  int beg = t * seg;
  int end = min(beg + seg, total);
  int sum = 0;
  for (int i = beg; i < end; ++i) sum += a[i];
  s[t] = sum;
  __syncthreads();
  for (int d = 1; d < 1024; d <<= 1) {
    int u = (t >= d) ? s[t - d] : 0;
    __syncthreads();
    s[t] += u;
    __syncthreads();
  }
  int run = s[t] - sum;                       // exclusive prefix
  for (int i = beg; i < end; ++i) { int v = a[i]; a[i] = run; run += v; }
}

// ---------------- phase 2: placement (write window ~40KB/block) ------
__global__ void k_part(const int* __restrict__ src, const int* __restrict__ dst,
                       const int* __restrict__ bases, unsigned int* __restrict__ part,
                       int E, int NB, int NCHUNK) {
  __shared__ int cur[512];
  int t = threadIdx.x;
  for (int d = t; d < NB; d += TPB) cur[d] = bases[d * NCHUNK + blockIdx.x];
  __syncthreads();
  int base = blockIdx.x * CHUNK;
  for (int i = t; i < CHUNK; i += TPB) {
    int e = base + i;
    if (e < E) {
      int dv = dst[e];
      int d = dv >> BKT_SHIFT;
      int p = atomicAdd(&cur[d], 1);
      part[p] = ((unsigned)src[e] << BKT_SHIFT) | (unsigned)(dv & (BKT_SZ - 1));
    }
  }
}

// ---------------- per-bucket degree -> dis = 1/sqrt(deg+1) -----------
__global__ void k_deg(const unsigned int* __restrict__ part, const int* __restrict__ bases,
                      float* __restrict__ dis, int n, int E, int NB, int NCHUNK) {
  __shared__ int cnt[BKT_SZ];
  int b = blockIdx.x, t = threadIdx.x;
  cnt[t] = 0;
  __syncthreads();
  int beg = bases[b * NCHUNK];
  int end = (b + 1 < NB) ? bases[(b + 1) * NCHUNK] : E;
  for (int e = beg + t; e < end; e += TPB)
    atomicAdd(&cnt[part[e] & (BKT_SZ - 1)], 1);
  __syncthreads();
  int node = b * BKT_SZ + t;
  if (node < n) dis[node] = 1.0f / sqrtf((float)(cnt[t] + 1));
}

// ---------------- layer 1 GEMM: h[i] = x[i] @ W1 (unscaled) ----------
// wave-per-node; each lane owns W1 rows [lane*8, lane*8+8) in 128 VGPRs.
__global__ __launch_bounds__(256) void k_gemm1(
    const float* __restrict__ x, const float* __restrict__ W1,
    float* __restrict__ h, int n, int nwaves) {
  const int lane = threadIdx.x & 63;
  const int wave = blockIdx.x * 4 + (threadIdx.x >> 6);

  float w[8][16];
  #pragma unroll
  for (int m = 0; m < 8; ++m) {
    #pragma unroll
    for (int q = 0; q < 4; ++q) {
      float4 t = *reinterpret_cast<const float4*>(W1 + (lane * 8 + m) * 16 + q * 4);
      w[m][q * 4 + 0] = t.x; w[m][q * 4 + 1] = t.y;
      w[m][q * 4 + 2] = t.z; w[m][q * 4 + 3] = t.w;
    }
  }
  // exchange-halves reduction leaves lane l owning column brev4(l&15)
  const int c_out = ((lane & 1) << 3) | ((lane & 2) << 1) | ((lane & 4) >> 1) | ((lane & 8) >> 3);

  for (int i = wave; i < n; i += nwaves) {
    const float4* xp = reinterpret_cast<const float4*>(x + (size_t)i * 512);
    float4 a = xp[lane * 2], b = xp[lane * 2 + 1];
    float xv[8] = {a.x, a.y, a.z, a.w, b.x, b.y, b.z, b.w};

    float acc[16];
    #pragma unroll
    for (int c = 0; c < 16; ++c) acc[c] = 0.f;
    #pragma unroll
    for (int m = 0; m < 8; ++m) {
      #pragma unroll
      for (int c = 0; c < 16; ++c) acc[c] = fmaf(xv[m], w[m][c], acc[c]);
    }

    {
      const bool hi = (lane & 1) != 0;
      #pragma unroll
      for (int v = 0; v < 8; ++v) {
        float send = hi ? acc[v] : acc[v + 8];
        float rcv = __shfl_xor(send, 1);
        acc[v] = (hi ? acc[v + 8] : acc[v]) + rcv;
      }
    }
    {
      const bool hi = (lane & 2) != 0;
      #pragma unroll
      for (int v = 0; v < 4; ++v) {
        float send = hi ? acc[v] : acc[v + 4];
        float rcv = __shfl_xor(send, 2);
        acc[v] = (hi ? acc[v + 4] : acc[v]) + rcv;
      }
    }
    {
      const bool hi = (lane & 4) != 0;
      #pragma unroll
      for (int v = 0; v < 2; ++v) {
        float send = hi ? acc[v] : acc[v + 2];
        float rcv = __shfl_xor(send, 4);
        acc[v] = (hi ? acc[v + 2] : acc[v]) + rcv;
      }
    }
    {
      const bool hi = (lane & 8) != 0;
      float send = hi ? acc[0] : acc[1];
      float rcv = __shfl_xor(send, 8);
      acc[0] = (hi ? acc[1] : acc[0]) + rcv;
    }
    float vsum = acc[0];
    vsum += __shfl_xor(vsum, 16);
    vsum += __shfl_xor(vsum, 32);

    if (lane < 16) h[(size_t)i * 16 + c_out] = vsum;
  }
}

// ------- layer 1 aggregate (LDS accum) + self-loop + ELU + prescale --
__global__ __launch_bounds__(512) void k_agg1(
    const unsigned int* __restrict__ part, const int* __restrict__ bases,
    const float* __restrict__ h, const float* __restrict__ dis,
    const float* __restrict__ b1, float* __restrict__ h1s,
    int n, int E, int NB, int NCHUNK) {
  __shared__ float acc[BKT_SZ * 16];
  int b = blockIdx.x, t = threadIdx.x;
  for (int u = t; u < BKT_SZ * 16; u += 512) acc[u] = 0.f;
  __syncthreads();
  int beg = bases[b * NCHUNK];
  int end = (b + 1 < NB) ? bases[(b + 1) * NCHUNK] : E;
  int c = t & 15, slot = t >> 4;              // 32 edge slots per block
  #pragma unroll 4
  for (int e = beg + slot; e < end; e += 32) {
    unsigned int en = part[e];
    int s = en >> BKT_SHIFT;
    int dl = en & (BKT_SZ - 1);
    float v = dis[s] * h[(size_t)s * 16 + c];
    atomicAdd(&acc[dl * 16 + c], v);
  }
  __syncthreads();
  for (int u = t; u < BKT_SZ * 16; u += 512) {
    int node = b * BKT_SZ + (u >> 4);
    if (node < n) {
      int cc = u & 15;
      float di = dis[node];
      float a = acc[u] + di * h[(size_t)node * 16 + cc];  // self loop
      float o = fmaf(di, a, b1[cc]);
      float h1 = o > 0.f ? o : expm1f(o);                  // elu
      h1s[(size_t)node * 16 + cc] = di * h1;               // layer-2 prescale
    }
  }
}

// ------- layer 2 aggregate + 16x16 matvec + bias + log_softmax -------
__global__ __launch_bounds__(512) void k_agg2(
    const unsigned int* __restrict__ part, const int* __restrict__ bases,
    const float* __restrict__ h1s, const float* __restrict__ dis,
    const float* __restrict__ W2, const float* __restrict__ b2,
    float* __restrict__ out, int n, int E, int NB, int NCHUNK) {
  __shared__ float acc[BKT_SZ * 16];
  __shared__ float w2s[256];
  int b = blockIdx.x, t = threadIdx.x;
  if (t < 256) w2s[t] = W2[t];
  for (int u = t; u < BKT_SZ * 16; u += 512) acc[u] = 0.f;
  __syncthreads();
  int beg = bases[b * NCHUNK];
  int end = (b + 1 < NB) ? bases[(b + 1) * NCHUNK] : E;
  int c = t & 15, slot = t >> 4;
  #pragma unroll 4
  for (int e = beg + slot; e < end; e += 32) {
    unsigned int en = part[e];
    int s = en >> BKT_SHIFT;
    int dl = en & (BKT_SZ - 1);
    atomicAdd(&acc[dl * 16 + c], h1s[(size_t)s * 16 + c]);
  }
  __syncthreads();
  for (int u = t; u < BKT_SZ * 16; u += 512) {       // self loop into acc
    int node = b * BKT_SZ + (u >> 4);
    if (node < n) acc[u] += h1s[(size_t)node * 16 + (u & 15)];
  }
  __syncthreads();
  for (int u = t; u < BKT_SZ * 16; u += 512) {
    int node = b * BKT_SZ + (u >> 4);
    int j = u >> 4, cc = u & 15;
    float o = 0.f;
    if (node < n) {
      float di = dis[node];
      float dot = 0.f;
      #pragma unroll
      for (int k = 0; k < 16; ++k)
        dot = fmaf(di * acc[j * 16 + k], w2s[k * 16 + cc], dot);
      o = dot + b2[cc];
    }
    // log_softmax across the 16-lane class group (group-uniform activity)
    float m = o;
    m = fmaxf(m, __shfl_xor(m, 1));
    m = fmaxf(m, __shfl_xor(m, 2));
    m = fmaxf(m, __shfl_xor(m, 4));
    m = fmaxf(m, __shfl_xor(m, 8));
    float ex = expf(o - m);
    float ssum = ex;
    ssum += __shfl_xor(ssum, 1);
    ssum += __shfl_xor(ssum, 2);
    ssum += __shfl_xor(ssum, 4);
    ssum += __shfl_xor(ssum, 8);
    if (node < n) out[(size_t)node * 16 + cc] = o - m - logf(ssum);
  }
}

// ---------------- launch ----------------
extern "C" void kernel_launch(void* const* d_in, const int* in_sizes, int n_in,
                              void* d_out, int out_size, void* d_ws, size_t ws_size,
                              hipStream_t stream) {
  const float* x  = (const float*)d_in[0];
  const int*   ei = (const int*)d_in[1];
  const float* W1 = (const float*)d_in[2];
  const float* b1 = (const float*)d_in[3];
  const float* W2 = (const float*)d_in[4];
  const float* b2 = (const float*)d_in[5];
  float* out = (float*)d_out;

  const int n = in_sizes[0] / 512;
  const int E = in_sizes[1] / 2;
  const int* src = ei;
  const int* dst = ei + E;

  const int NB = (n + BKT_SZ - 1) >> BKT_SHIFT;       // 391 buckets
  const int NCHUNK = (E + CHUNK - 1) / CHUNK;         // 391 chunks

  char* ws = (char*)d_ws;
  size_t off = 0;
  auto alloc = [&](size_t bytes) -> void* {
    void* p = (void*)(ws + off);
    off += (bytes + 255) & ~(size_t)255;
    return p;
  };
  int*          counts = (int*)alloc((size_t)NB * NCHUNK * 4);
  unsigned int* part   = (unsigned int*)alloc((size_t)E * 4);
  float*        dis    = (float*)alloc((size_t)n * 4);
  float*        h      = (float*)alloc((size_t)n * 16 * 4);
  float*        h1s    = (float*)alloc((size_t)n * 16 * 4);
  (void)ws_size; (void)n_in; (void)out_size;

  k_count<<<NCHUNK, TPB, 0, stream>>>(dst, counts, E, NB, NCHUNK);
  k_scan <<<1, 1024, 0, stream>>>(counts, NB * NCHUNK);
  k_part <<<NCHUNK, TPB, 0, stream>>>(src, dst, counts, part, E, NB, NCHUNK);
  k_deg  <<<NB, TPB, 0, stream>>>(part, counts, dis, n, E, NB, NCHUNK);
  k_gemm1<<<2048, TPB, 0, stream>>>(x, W1, h, n, 2048 * 4);
  k_agg1 <<<NB, 512, 0, stream>>>(part, counts, h, dis, b1, h1s, n, E, NB, NCHUNK);
  k_agg2 <<<NB, 512, 0, stream>>>(part, counts, h1s, dis, W2, b2, out, n, E, NB, NCHUNK);
}

// Round 3
// 798.959 us; speedup vs baseline: 1.6770x; 1.6770x over previous
//
#include <hip/hip_runtime.h>

#define TPB 256
#define BKT_SHIFT 8
#define BKT_SZ 256
#define CHUNK 8192

// ---------------- phase 1: per-chunk bucket histogram ----------------
__global__ void k_count(const int* __restrict__ dst, int* __restrict__ counts,
                        int E, int NB, int NCHUNK) {
  __shared__ int hist[512];
  int t = threadIdx.x;
  for (int d = t; d < NB; d += TPB) hist[d] = 0;
  __syncthreads();
  int base = blockIdx.x * CHUNK;
  for (int i = t; i < CHUNK; i += TPB) {
    int e = base + i;
    if (e < E) atomicAdd(&hist[dst[e] >> BKT_SHIFT], 1);
  }
  __syncthreads();
  for (int d = t; d < NB; d += TPB)
    counts[d * NCHUNK + blockIdx.x] = hist[d];
}

// ---------------- global exclusive scan (single block, 1024 thr) -----
__global__ void k_scan(int* __restrict__ a, int total) {
  __shared__ int s[1024];
  int t = threadIdx.x;
  int seg = (total + 1023) >> 10;
  int beg = t * seg;
  int end = min(beg + seg, total);
  int sum = 0;
  for (int i = beg; i < end; ++i) sum += a[i];
  s[t] = sum;
  __syncthreads();
  for (int d = 1; d < 1024; d <<= 1) {
    int u = (t >= d) ? s[t - d] : 0;
    __syncthreads();
    s[t] += u;
    __syncthreads();
  }
  int run = s[t] - sum;                       // exclusive prefix
  for (int i = beg; i < end; ++i) { int v = a[i]; a[i] = run; run += v; }
}

// ---------------- phase 2: bucket partition (packed (src<<8)|dl) -----
__global__ void k_part(const int* __restrict__ src, const int* __restrict__ dst,
                       const int* __restrict__ bases, unsigned int* __restrict__ part,
                       int E, int NB, int NCHUNK) {
  __shared__ int cur[512];
  int t = threadIdx.x;
  for (int d = t; d < NB; d += TPB) cur[d] = bases[d * NCHUNK + blockIdx.x];
  __syncthreads();
  int base = blockIdx.x * CHUNK;
  for (int i = t; i < CHUNK; i += TPB) {
    int e = base + i;
    if (e < E) {
      int dv = dst[e];
      int d = dv >> BKT_SHIFT;
      int p = atomicAdd(&cur[d], 1);
      part[p] = ((unsigned)src[e] << BKT_SHIFT) | (unsigned)(dv & (BKT_SZ - 1));
    }
  }
}

// ------- phase 3: per-bucket CSR finalize: offs, dis, csr ------------
// one block per bucket; all atomics in LDS; csr writes stay in a
// contiguous per-block 32KB region (single-XCD, L2-merged).
__global__ __launch_bounds__(256) void k_build(
    const unsigned int* __restrict__ part, const int* __restrict__ bases,
    int* __restrict__ offs, int* __restrict__ csr, float* __restrict__ dis,
    int n, int E, int NB, int NCHUNK) {
  __shared__ int cnt[BKT_SZ];
  __shared__ int scn[BKT_SZ];
  int b = blockIdx.x, t = threadIdx.x;
  cnt[t] = 0;
  __syncthreads();
  int beg = bases[b * NCHUNK];
  int end = (b + 1 < NB) ? bases[(b + 1) * NCHUNK] : E;
  for (int e = beg + t; e < end; e += 256)
    atomicAdd(&cnt[part[e] & (BKT_SZ - 1)], 1);
  __syncthreads();
  int deg = cnt[t];
  scn[t] = deg;
  __syncthreads();
  for (int d = 1; d < 256; d <<= 1) {
    int u = (t >= d) ? scn[t - d] : 0;
    __syncthreads();
    scn[t] += u;
    __syncthreads();
  }
  int excl = scn[t] - deg;
  int node = b * BKT_SZ + t;
  if (node < n) {
    offs[node] = beg + excl;
    dis[node] = 1.0f / sqrtf((float)(deg + 1));   // +1 self loop
  }
  if (b == NB - 1 && t == 0) offs[n] = E;
  __syncthreads();
  cnt[t] = beg + excl;                            // reuse as cursor
  __syncthreads();
  for (int e = beg + t; e < end; e += 256) {
    unsigned int en = part[e];
    int p = atomicAdd(&cnt[en & (BKT_SZ - 1)], 1);
    csr[p] = (int)(en >> BKT_SHIFT);
  }
}

// ---------------- layer 1 GEMM: hs[i] = dis[i] * (x[i] @ W1) ---------
// wave-per-node; each lane owns W1 rows [lane*8, lane*8+8) in 128 VGPRs.
__global__ __launch_bounds__(256) void k_gemm1(
    const float* __restrict__ x, const float* __restrict__ W1,
    const float* __restrict__ dis, float* __restrict__ hs, int n, int nwaves) {
  const int lane = threadIdx.x & 63;
  const int wave = blockIdx.x * 4 + (threadIdx.x >> 6);

  float w[8][16];
  #pragma unroll
  for (int m = 0; m < 8; ++m) {
    #pragma unroll
    for (int q = 0; q < 4; ++q) {
      float4 t = *reinterpret_cast<const float4*>(W1 + (lane * 8 + m) * 16 + q * 4);
      w[m][q * 4 + 0] = t.x; w[m][q * 4 + 1] = t.y;
      w[m][q * 4 + 2] = t.z; w[m][q * 4 + 3] = t.w;
    }
  }
  // exchange-halves reduction leaves lane l owning column brev4(l&15)
  const int c_out = ((lane & 1) << 3) | ((lane & 2) << 1) | ((lane & 4) >> 1) | ((lane & 8) >> 3);

  for (int i = wave; i < n; i += nwaves) {
    const float4* xp = reinterpret_cast<const float4*>(x + (size_t)i * 512);
    float4 a = xp[lane * 2], b = xp[lane * 2 + 1];
    float xv[8] = {a.x, a.y, a.z, a.w, b.x, b.y, b.z, b.w};

    float acc[16];
    #pragma unroll
    for (int c = 0; c < 16; ++c) acc[c] = 0.f;
    #pragma unroll
    for (int m = 0; m < 8; ++m) {
      #pragma unroll
      for (int c = 0; c < 16; ++c) acc[c] = fmaf(xv[m], w[m][c], acc[c]);
    }

    {
      const bool hi = (lane & 1) != 0;
      #pragma unroll
      for (int v = 0; v < 8; ++v) {
        float send = hi ? acc[v] : acc[v + 8];
        float rcv = __shfl_xor(send, 1);
        acc[v] = (hi ? acc[v + 8] : acc[v]) + rcv;
      }
    }
    {
      const bool hi = (lane & 2) != 0;
      #pragma unroll
      for (int v = 0; v < 4; ++v) {
        float send = hi ? acc[v] : acc[v + 4];
        float rcv = __shfl_xor(send, 2);
        acc[v] = (hi ? acc[v + 4] : acc[v]) + rcv;
      }
    }
    {
      const bool hi = (lane & 4) != 0;
      #pragma unroll
      for (int v = 0; v < 2; ++v) {
        float send = hi ? acc[v] : acc[v + 2];
        float rcv = __shfl_xor(send, 4);
        acc[v] = (hi ? acc[v + 2] : acc[v]) + rcv;
      }
    }
    {
      const bool hi = (lane & 8) != 0;
      float send = hi ? acc[0] : acc[1];
      float rcv = __shfl_xor(send, 8);
      acc[0] = (hi ? acc[1] : acc[0]) + rcv;
    }
    float vsum = acc[0];
    vsum += __shfl_xor(vsum, 16);
    vsum += __shfl_xor(vsum, 32);

    if (lane < 16) hs[(size_t)i * 16 + c_out] = dis[i] * vsum;
  }
}

// ------- layer 1 aggregate + self-loop + ELU + layer-2 prescale ------
// wave-per-dst-node: 16 cols x 4 edge slots; gather-only, no atomics.
__global__ __launch_bounds__(256) void k_agg1(
    const int* __restrict__ offs, const int* __restrict__ csr,
    const float* __restrict__ hs, const float* __restrict__ dis,
    const float* __restrict__ b1, float* __restrict__ h1s, int n) {
  int wave = blockIdx.x * 4 + (threadIdx.x >> 6);
  if (wave >= n) return;
  int lane = threadIdx.x & 63;
  int c = lane & 15, r = lane >> 4;
  int beg = offs[wave], end = offs[wave + 1];
  float acc = 0.f;
  #pragma unroll 2
  for (int k = beg + r; k < end; k += 4)
    acc += hs[(size_t)csr[k] * 16 + c];
  acc += __shfl_xor(acc, 16);
  acc += __shfl_xor(acc, 32);
  acc += hs[(size_t)wave * 16 + c];          // self loop
  float di = dis[wave];
  float o = fmaf(di, acc, b1[c]);
  float h1 = o > 0.f ? o : expm1f(o);        // elu, alpha=1
  if (r == 0) h1s[(size_t)wave * 16 + c] = di * h1;
}

// ------- layer 2 aggregate + 16x16 matvec + bias + log_softmax -------
__global__ __launch_bounds__(256) void k_agg2(
    const int* __restrict__ offs, const int* __restrict__ csr,
    const float* __restrict__ h1s, const float* __restrict__ dis,
    const float* __restrict__ W2, const float* __restrict__ b2,
    float* __restrict__ out, int n) {
  __shared__ float w2s[256];
  w2s[threadIdx.x] = W2[threadIdx.x];
  __syncthreads();
  int wave = blockIdx.x * 4 + (threadIdx.x >> 6);
  if (wave >= n) return;
  int lane = threadIdx.x & 63;
  int c = lane & 15, r = lane >> 4;
  int beg = offs[wave], end = offs[wave + 1];
  float acc = 0.f;
  #pragma unroll 2
  for (int k = beg + r; k < end; k += 4)
    acc += h1s[(size_t)csr[k] * 16 + c];
  acc += __shfl_xor(acc, 16);
  acc += __shfl_xor(acc, 32);
  acc += h1s[(size_t)wave * 16 + c];         // self loop
  float di = dis[wave];
  float dot = 0.f;
  #pragma unroll
  for (int k = 0; k < 16; ++k) {
    float vk = __shfl(acc, k, 16);           // broadcast feature k within 16-group
    dot = fmaf(di * vk, w2s[k * 16 + c], dot);
  }
  float o = dot + b2[c];
  // log_softmax over the 16 class lanes
  float m = o;
  m = fmaxf(m, __shfl_xor(m, 1));
  m = fmaxf(m, __shfl_xor(m, 2));
  m = fmaxf(m, __shfl_xor(m, 4));
  m = fmaxf(m, __shfl_xor(m, 8));
  float ex = expf(o - m);
  float ssum = ex;
  ssum += __shfl_xor(ssum, 1);
  ssum += __shfl_xor(ssum, 2);
  ssum += __shfl_xor(ssum, 4);
  ssum += __shfl_xor(ssum, 8);
  if (r == 0) out[(size_t)wave * 16 + c] = o - m - logf(ssum);
}

// ---------------- launch ----------------
extern "C" void kernel_launch(void* const* d_in, const int* in_sizes, int n_in,
                              void* d_out, int out_size, void* d_ws, size_t ws_size,
                              hipStream_t stream) {
  const float* x  = (const float*)d_in[0];
  const int*   ei = (const int*)d_in[1];
  const float* W1 = (const float*)d_in[2];
  const float* b1 = (const float*)d_in[3];
  const float* W2 = (const float*)d_in[4];
  const float* b2 = (const float*)d_in[5];
  float* out = (float*)d_out;

  const int n = in_sizes[0] / 512;
  const int E = in_sizes[1] / 2;
  const int* src = ei;
  const int* dst = ei + E;

  const int NB = (n + BKT_SZ - 1) >> BKT_SHIFT;       // 391 buckets
  const int NCHUNK = (E + CHUNK - 1) / CHUNK;         // 391 chunks

  char* ws = (char*)d_ws;
  size_t off = 0;
  auto alloc = [&](size_t bytes) -> void* {
    void* p = (void*)(ws + off);
    off += (bytes + 255) & ~(size_t)255;
    return p;
  };
  int*          counts = (int*)alloc((size_t)NB * NCHUNK * 4);
  unsigned int* part   = (unsigned int*)alloc((size_t)E * 4);
  int*          offs   = (int*)alloc((size_t)(n + 1) * 4);
  int*          csr    = (int*)alloc((size_t)E * 4);
  float*        dis    = (float*)alloc((size_t)n * 4);
  float*        hs     = (float*)alloc((size_t)n * 16 * 4);
  float*        h1s    = (float*)alloc((size_t)n * 16 * 4);
  (void)ws_size; (void)n_in; (void)out_size;

  const int ab = (n + 3) / 4;                         // 4 nodes per block

  k_count<<<NCHUNK, TPB, 0, stream>>>(dst, counts, E, NB, NCHUNK);
  k_scan <<<1, 1024, 0, stream>>>(counts, NB * NCHUNK);
  k_part <<<NCHUNK, TPB, 0, stream>>>(src, dst, counts, part, E, NB, NCHUNK);
  k_build<<<NB, TPB, 0, stream>>>(part, counts, offs, csr, dis, n, E, NB, NCHUNK);
  k_gemm1<<<2048, TPB, 0, stream>>>(x, W1, dis, hs, n, 2048 * 4);
  k_agg1 <<<ab, TPB, 0, stream>>>(offs, csr, hs, dis, b1, h1s, n);
  k_agg2 <<<ab, TPB, 0, stream>>>(offs, csr, h1s, dis, W2, b2, out, n);
}

// Round 5
// 558.524 us; speedup vs baseline: 2.3989x; 1.4305x over previous
//
#include <hip/hip_runtime.h>

#define TPB 256
#define BKT_SHIFT 8
#define BKT_SZ 256
#define CHUNK 8192

// ---------------- phase 1: per-chunk bucket histogram ----------------
__global__ void k_count(const int* __restrict__ dst, int* __restrict__ counts,
                        int E, int NB, int NCHUNK) {
  __shared__ int hist[512];
  int t = threadIdx.x;
  for (int d = t; d < NB; d += TPB) hist[d] = 0;
  __syncthreads();
  int base = blockIdx.x * CHUNK;
  for (int i = t; i < CHUNK; i += TPB) {
    int e = base + i;
    if (e < E) atomicAdd(&hist[dst[e] >> BKT_SHIFT], 1);
  }
  __syncthreads();
  for (int d = t; d < NB; d += TPB)
    counts[d * NCHUNK + blockIdx.x] = hist[d];
}

// ------- hierarchical exclusive scan over counts (3 kernels) ---------
__global__ void k_scan1(int* __restrict__ a, int* __restrict__ btot, int total) {
  __shared__ int s[TPB];
  int t = threadIdx.x;
  int i = blockIdx.x * TPB + t;
  int v = (i < total) ? a[i] : 0;
  s[t] = v;
  __syncthreads();
  for (int d = 1; d < TPB; d <<= 1) {
    int u = (t >= d) ? s[t - d] : 0;
    __syncthreads();
    s[t] += u;
    __syncthreads();
  }
  if (i < total) a[i] = s[t] - v;             // exclusive within block
  if (t == TPB - 1) btot[blockIdx.x] = s[t];
}

__global__ void k_scan2(int* __restrict__ btot, int nb) {   // nb <= 1024
  __shared__ int s[1024];
  int t = threadIdx.x;
  int v = (t < nb) ? btot[t] : 0;
  s[t] = v;
  __syncthreads();
  for (int d = 1; d < 1024; d <<= 1) {
    int u = (t >= d) ? s[t - d] : 0;
    __syncthreads();
    s[t] += u;
    __syncthreads();
  }
  if (t < nb) btot[t] = s[t] - v;             // exclusive
}

__global__ void k_scan3(int* __restrict__ a, const int* __restrict__ btot, int total) {
  int i = blockIdx.x * TPB + threadIdx.x;
  if (i < total) a[i] += btot[blockIdx.x];
}

// ---------------- phase 2: bucket partition (packed (src<<8)|dl) -----
__global__ void k_part(const int* __restrict__ src, const int* __restrict__ dst,
                       const int* __restrict__ bases, unsigned int* __restrict__ part,
                       int E, int NB, int NCHUNK) {
  __shared__ int cur[512];
  int t = threadIdx.x;
  for (int d = t; d < NB; d += TPB) cur[d] = bases[d * NCHUNK + blockIdx.x];
  __syncthreads();
  int base = blockIdx.x * CHUNK;
  for (int i = t; i < CHUNK; i += TPB) {
    int e = base + i;
    if (e < E) {
      int dv = dst[e];
      int d = dv >> BKT_SHIFT;
      int p = atomicAdd(&cur[d], 1);
      part[p] = ((unsigned)src[e] << BKT_SHIFT) | (unsigned)(dv & (BKT_SZ - 1));
    }
  }
}

// ------- phase 3: per-bucket CSR finalize: offs, dis, csr ------------
__global__ __launch_bounds__(256) void k_build(
    const unsigned int* __restrict__ part, const int* __restrict__ bases,
    int* __restrict__ offs, int* __restrict__ csr, float* __restrict__ dis,
    int n, int E, int NB, int NCHUNK) {
  __shared__ int cnt[BKT_SZ];
  __shared__ int scn[BKT_SZ];
  int b = blockIdx.x, t = threadIdx.x;
  cnt[t] = 0;
  __syncthreads();
  int beg = bases[b * NCHUNK];
  int end = (b + 1 < NB) ? bases[(b + 1) * NCHUNK] : E;
  for (int e = beg + t; e < end; e += 256)
    atomicAdd(&cnt[part[e] & (BKT_SZ - 1)], 1);
  __syncthreads();
  int deg = cnt[t];
  scn[t] = deg;
  __syncthreads();
  for (int d = 1; d < 256; d <<= 1) {
    int u = (t >= d) ? scn[t - d] : 0;
    __syncthreads();
    scn[t] += u;
    __syncthreads();
  }
  int excl = scn[t] - deg;
  int node = b * BKT_SZ + t;
  if (node < n) {
    offs[node] = beg + excl;
    dis[node] = 1.0f / sqrtf((float)(deg + 1));   // +1 self loop
  }
  if (b == NB - 1 && t == 0) offs[n] = E;
  __syncthreads();
  cnt[t] = beg + excl;                            // reuse as cursor
  __syncthreads();
  for (int e = beg + t; e < end; e += 256) {
    unsigned int en = part[e];
    int p = atomicAdd(&cnt[en & (BKT_SZ - 1)], 1);
    csr[p] = (int)(en >> BKT_SHIFT);
  }
}

// ---------------- layer 1 GEMM: hs[i] = dis[i] * (x[i] @ W1) ---------
// wave-per-node; each lane owns W1 rows [lane*8, lane*8+8) in 128 VGPRs.
__global__ __launch_bounds__(256) void k_gemm1(
    const float* __restrict__ x, const float* __restrict__ W1,
    const float* __restrict__ dis, float* __restrict__ hs, int n, int nwaves) {
  const int lane = threadIdx.x & 63;
  const int wave = blockIdx.x * 4 + (threadIdx.x >> 6);

  float w[8][16];
  #pragma unroll
  for (int m = 0; m < 8; ++m) {
    #pragma unroll
    for (int q = 0; q < 4; ++q) {
      float4 t = *reinterpret_cast<const float4*>(W1 + (lane * 8 + m) * 16 + q * 4);
      w[m][q * 4 + 0] = t.x; w[m][q * 4 + 1] = t.y;
      w[m][q * 4 + 2] = t.z; w[m][q * 4 + 3] = t.w;
    }
  }
  // exchange-halves reduction leaves lane l owning column brev4(l&15)
  const int c_out = ((lane & 1) << 3) | ((lane & 2) << 1) | ((lane & 4) >> 1) | ((lane & 8) >> 3);

  for (int i = wave; i < n; i += nwaves) {
    const float4* xp = reinterpret_cast<const float4*>(x + (size_t)i * 512);
    float4 a = xp[lane * 2], b = xp[lane * 2 + 1];
    float xv[8] = {a.x, a.y, a.z, a.w, b.x, b.y, b.z, b.w};

    float acc[16];
    #pragma unroll
    for (int c = 0; c < 16; ++c) acc[c] = 0.f;
    #pragma unroll
    for (int m = 0; m < 8; ++m) {
      #pragma unroll
      for (int c = 0; c < 16; ++c) acc[c] = fmaf(xv[m], w[m][c], acc[c]);
    }

    {
      const bool hi = (lane & 1) != 0;
      #pragma unroll
      for (int v = 0; v < 8; ++v) {
        float send = hi ? acc[v] : acc[v + 8];
        float rcv = __shfl_xor(send, 1);
        acc[v] = (hi ? acc[v + 8] : acc[v]) + rcv;
      }
    }
    {
      const bool hi = (lane & 2) != 0;
      #pragma unroll
      for (int v = 0; v < 4; ++v) {
        float send = hi ? acc[v] : acc[v + 4];
        float rcv = __shfl_xor(send, 2);
        acc[v] = (hi ? acc[v + 4] : acc[v]) + rcv;
      }
    }
    {
      const bool hi = (lane & 4) != 0;
      #pragma unroll
      for (int v = 0; v < 2; ++v) {
        float send = hi ? acc[v] : acc[v + 2];
        float rcv = __shfl_xor(send, 4);
        acc[v] = (hi ? acc[v + 2] : acc[v]) + rcv;
      }
    }
    {
      const bool hi = (lane & 8) != 0;
      float send = hi ? acc[0] : acc[1];
      float rcv = __shfl_xor(send, 8);
      acc[0] = (hi ? acc[1] : acc[0]) + rcv;
    }
    float vsum = acc[0];
    vsum += __shfl_xor(vsum, 16);
    vsum += __shfl_xor(vsum, 32);

    if (lane < 16) hs[(size_t)i * 16 + c_out] = dis[i] * vsum;
  }
}

// ------- layer 1 aggregate + self-loop + ELU + layer-2 prescale ------
// wave-per-dst-node: 16 cols x 4 edge slots; gather-only, no atomics.
__global__ __launch_bounds__(256) void k_agg1(
    const int* __restrict__ offs, const int* __restrict__ csr,
    const float* __restrict__ hs, const float* __restrict__ dis,
    const float* __restrict__ b1, float* __restrict__ h1s, int n) {
  int wave = blockIdx.x * 4 + (threadIdx.x >> 6);
  if (wave >= n) return;
  int lane = threadIdx.x & 63;
  int c = lane & 15, r = lane >> 4;
  int beg = offs[wave], end = offs[wave + 1];
  float acc = 0.f;
  #pragma unroll 2
  for (int k = beg + r; k < end; k += 4)
    acc += hs[(size_t)csr[k] * 16 + c];
  acc += __shfl_xor(acc, 16);
  acc += __shfl_xor(acc, 32);
  acc += hs[(size_t)wave * 16 + c];          // self loop
  float di = dis[wave];
  float o = fmaf(di, acc, b1[c]);
  float h1 = o > 0.f ? o : expm1f(o);        // elu, alpha=1
  if (r == 0) h1s[(size_t)wave * 16 + c] = di * h1;
}

// ------- layer 2 aggregate + 16x16 matvec + bias + log_softmax -------
__global__ __launch_bounds__(256) void k_agg2(
    const int* __restrict__ offs, const int* __restrict__ csr,
    const float* __restrict__ h1s, const float* __restrict__ dis,
    const float* __restrict__ W2, const float* __restrict__ b2,
    float* __restrict__ out, int n) {
  __shared__ float w2s[256];
  w2s[threadIdx.x] = W2[threadIdx.x];
  __syncthreads();
  int wave = blockIdx.x * 4 + (threadIdx.x >> 6);
  if (wave >= n) return;
  int lane = threadIdx.x & 63;
  int c = lane & 15, r = lane >> 4;
  int beg = offs[wave], end = offs[wave + 1];
  float acc = 0.f;
  #pragma unroll 2
  for (int k = beg + r; k < end; k += 4)
    acc += h1s[(size_t)csr[k] * 16 + c];
  acc += __shfl_xor(acc, 16);
  acc += __shfl_xor(acc, 32);
  acc += h1s[(size_t)wave * 16 + c];         // self loop
  float di = dis[wave];
  float dot = 0.f;
  #pragma unroll
  for (int k = 0; k < 16; ++k) {
    float vk = __shfl(acc, k, 16);           // broadcast feature k within 16-group
    dot = fmaf(di * vk, w2s[k * 16 + c], dot);
  }
  float o = dot + b2[c];
  // log_softmax over the 16 class lanes
  float m = o;
  m = fmaxf(m, __shfl_xor(m, 1));
  m = fmaxf(m, __shfl_xor(m, 2));
  m = fmaxf(m, __shfl_xor(m, 4));
  m = fmaxf(m, __shfl_xor(m, 8));
  float ex = expf(o - m);
  float ssum = ex;
  ssum += __shfl_xor(ssum, 1);
  ssum += __shfl_xor(ssum, 2);
  ssum += __shfl_xor(ssum, 4);
  ssum += __shfl_xor(ssum, 8);
  if (r == 0) out[(size_t)wave * 16 + c] = o - m - logf(ssum);
}

// ---------------- launch ----------------
extern "C" void kernel_launch(void* const* d_in, const int* in_sizes, int n_in,
                              void* d_out, int out_size, void* d_ws, size_t ws_size,
                              hipStream_t stream) {
  const float* x  = (const float*)d_in[0];
  const int*   ei = (const int*)d_in[1];
  const float* W1 = (const float*)d_in[2];
  const float* b1 = (const float*)d_in[3];
  const float* W2 = (const float*)d_in[4];
  const float* b2 = (const float*)d_in[5];
  float* out = (float*)d_out;

  const int n = in_sizes[0] / 512;
  const int E = in_sizes[1] / 2;
  const int* src = ei;
  const int* dst = ei + E;

  const int NB = (n + BKT_SZ - 1) >> BKT_SHIFT;       // 391 buckets
  const int NCHUNK = (E + CHUNK - 1) / CHUNK;         // 391 chunks
  const int total = NB * NCHUNK;                      // 152881
  const int sb = (total + TPB - 1) / TPB;             // 598 scan blocks

  char* ws = (char*)d_ws;
  size_t off = 0;
  auto alloc = [&](size_t bytes) -> void* {
    void* p = (void*)(ws + off);
    off += (bytes + 255) & ~(size_t)255;
    return p;
  };
  int*          counts = (int*)alloc((size_t)total * 4);
  int*          btot   = (int*)alloc(1024 * 4);
  unsigned int* part   = (unsigned int*)alloc((size_t)E * 4);
  int*          offs   = (int*)alloc((size_t)(n + 1) * 4);
  int*          csr    = (int*)alloc((size_t)E * 4);
  float*        dis    = (float*)alloc((size_t)n * 4);
  float*        hs     = (float*)alloc((size_t)n * 16 * 4);
  float*        h1s    = (float*)alloc((size_t)n * 16 * 4);
  (void)ws_size; (void)n_in; (void)out_size;

  const int ab = (n + 3) / 4;                         // 4 nodes per block

  k_count<<<NCHUNK, TPB, 0, stream>>>(dst, counts, E, NB, NCHUNK);
  k_scan1<<<sb, TPB, 0, stream>>>(counts, btot, total);
  k_scan2<<<1, 1024, 0, stream>>>(btot, sb);
  k_scan3<<<sb, TPB, 0, stream>>>(counts, btot, total);
  k_part <<<NCHUNK, TPB, 0, stream>>>(src, dst, counts, part, E, NB, NCHUNK);
  k_build<<<NB, TPB, 0, stream>>>(part, counts, offs, csr, dis, n, E, NB, NCHUNK);
  k_gemm1<<<2048, TPB, 0, stream>>>(x, W1, dis, hs, n, 2048 * 4);
  k_agg1 <<<ab, TPB, 0, stream>>>(offs, csr, hs, dis, b1, h1s, n);
  k_agg2 <<<ab, TPB, 0, stream>>>(offs, csr, h1s, dis, W2, b2, out, n);
}

// Round 6
// 543.846 us; speedup vs baseline: 2.4636x; 1.0270x over previous
//
#include <hip/hip_runtime.h>

#define TPB 256
#define BKT_SHIFT 8
#define BKT_SZ 256
#define CHUNK 8192

// ---------------- phase 1: per-chunk bucket histogram ----------------
__global__ void k_count(const int* __restrict__ dst, int* __restrict__ counts,
                        int E, int NB, int NCHUNK) {
  __shared__ int hist[512];
  int t = threadIdx.x;
  for (int d = t; d < NB; d += TPB) hist[d] = 0;
  __syncthreads();
  int base = blockIdx.x * CHUNK;
  for (int i = t; i < CHUNK; i += TPB) {
    int e = base + i;
    if (e < E) atomicAdd(&hist[dst[e] >> BKT_SHIFT], 1);
  }
  __syncthreads();
  for (int d = t; d < NB; d += TPB)
    counts[d * NCHUNK + blockIdx.x] = hist[d];
}

// ------- hierarchical exclusive scan over counts (2 kernels; the ----
// ------- "add block base" pass is folded into k_part / k_build) -----
__global__ void k_scan1(int* __restrict__ a, int* __restrict__ btot, int total) {
  __shared__ int s[TPB];
  int t = threadIdx.x;
  int i = blockIdx.x * TPB + t;
  int v = (i < total) ? a[i] : 0;
  s[t] = v;
  __syncthreads();
  for (int d = 1; d < TPB; d <<= 1) {
    int u = (t >= d) ? s[t - d] : 0;
    __syncthreads();
    s[t] += u;
    __syncthreads();
  }
  if (i < total) a[i] = s[t] - v;             // exclusive within block
  if (t == TPB - 1) btot[blockIdx.x] = s[t];
}

__global__ void k_scan2(int* __restrict__ btot, int nb) {   // nb <= 1024
  __shared__ int s[1024];
  int t = threadIdx.x;
  int v = (t < nb) ? btot[t] : 0;
  s[t] = v;
  __syncthreads();
  for (int d = 1; d < 1024; d <<= 1) {
    int u = (t >= d) ? s[t - d] : 0;
    __syncthreads();
    s[t] += u;
    __syncthreads();
  }
  if (t < nb) btot[t] = s[t] - v;             // exclusive
}

// ---------------- phase 2: bucket partition (packed (src<<8)|dl) -----
__global__ void k_part(const int* __restrict__ src, const int* __restrict__ dst,
                       const int* __restrict__ cnts, const int* __restrict__ btot,
                       unsigned int* __restrict__ part, int E, int NB, int NCHUNK) {
  __shared__ int cur[512];
  int t = threadIdx.x;
  for (int d = t; d < NB; d += TPB) {
    int idx = d * NCHUNK + blockIdx.x;
    cur[d] = cnts[idx] + btot[idx >> 8];
  }
  __syncthreads();
  int base = blockIdx.x * CHUNK;
  for (int i = t; i < CHUNK; i += TPB) {
    int e = base + i;
    if (e < E) {
      int dv = dst[e];
      int d = dv >> BKT_SHIFT;
      int p = atomicAdd(&cur[d], 1);
      part[p] = ((unsigned)src[e] << BKT_SHIFT) | (unsigned)(dv & (BKT_SZ - 1));
    }
  }
}

// ------- phase 3: per-bucket CSR finalize: offs, dis, csr ------------
__global__ __launch_bounds__(256) void k_build(
    const unsigned int* __restrict__ part, const int* __restrict__ cnts,
    const int* __restrict__ btot,
    int* __restrict__ offs, int* __restrict__ csr, float* __restrict__ dis,
    int n, int E, int NB, int NCHUNK) {
  __shared__ int cnt[BKT_SZ];
  __shared__ int scn[BKT_SZ];
  int b = blockIdx.x, t = threadIdx.x;
  cnt[t] = 0;
  __syncthreads();
  int i0 = b * NCHUNK;
  int beg = cnts[i0] + btot[i0 >> 8];
  int end = E;
  if (b + 1 < NB) {
    int i1 = (b + 1) * NCHUNK;
    end = cnts[i1] + btot[i1 >> 8];
  }
  for (int e = beg + t; e < end; e += 256)
    atomicAdd(&cnt[part[e] & (BKT_SZ - 1)], 1);
  __syncthreads();
  int deg = cnt[t];
  scn[t] = deg;
  __syncthreads();
  for (int d = 1; d < 256; d <<= 1) {
    int u = (t >= d) ? scn[t - d] : 0;
    __syncthreads();
    scn[t] += u;
    __syncthreads();
  }
  int excl = scn[t] - deg;
  int node = b * BKT_SZ + t;
  if (node < n) {
    offs[node] = beg + excl;
    dis[node] = 1.0f / sqrtf((float)(deg + 1));   // +1 self loop
  }
  if (b == NB - 1 && t == 0) offs[n] = E;
  __syncthreads();
  cnt[t] = beg + excl;                            // reuse as cursor
  __syncthreads();
  for (int e = beg + t; e < end; e += 256) {
    unsigned int en = part[e];
    int p = atomicAdd(&cnt[en & (BKT_SZ - 1)], 1);
    csr[p] = (int)(en >> BKT_SHIFT);
  }
}

// ---------------- layer 1 GEMM: hs[i] = dis[i] * (x[i] @ W1) ---------
// wave-per-node; each lane owns W1 rows [lane*8, lane*8+8) in 128 VGPRs.
// Node-ahead prefetch of x to hide HBM latency at ~3 waves/SIMD.
__global__ __launch_bounds__(256) void k_gemm1(
    const float* __restrict__ x, const float* __restrict__ W1,
    const float* __restrict__ dis, float* __restrict__ hs, int n, int nwaves) {
  const int lane = threadIdx.x & 63;
  const int wave = blockIdx.x * 4 + (threadIdx.x >> 6);

  float w[8][16];
  #pragma unroll
  for (int m = 0; m < 8; ++m) {
    #pragma unroll
    for (int q = 0; q < 4; ++q) {
      float4 t = *reinterpret_cast<const float4*>(W1 + (lane * 8 + m) * 16 + q * 4);
      w[m][q * 4 + 0] = t.x; w[m][q * 4 + 1] = t.y;
      w[m][q * 4 + 2] = t.z; w[m][q * 4 + 3] = t.w;
    }
  }
  // exchange-halves reduction leaves lane l owning column brev4(l&15)
  const int c_out = ((lane & 1) << 3) | ((lane & 2) << 1) | ((lane & 4) >> 1) | ((lane & 8) >> 3);

  float4 a = {0, 0, 0, 0}, b = {0, 0, 0, 0};
  if (wave < n) {
    const float4* xp = reinterpret_cast<const float4*>(x + (size_t)wave * 512);
    a = xp[lane * 2]; b = xp[lane * 2 + 1];
  }

  for (int i = wave; i < n; ) {
    int inext = i + nwaves;
    float4 an = {0, 0, 0, 0}, bn = {0, 0, 0, 0};
    if (inext < n) {
      const float4* xp = reinterpret_cast<const float4*>(x + (size_t)inext * 512);
      an = xp[lane * 2]; bn = xp[lane * 2 + 1];
    }

    float xv[8] = {a.x, a.y, a.z, a.w, b.x, b.y, b.z, b.w};
    float acc[16];
    #pragma unroll
    for (int c = 0; c < 16; ++c) acc[c] = 0.f;
    #pragma unroll
    for (int m = 0; m < 8; ++m) {
      #pragma unroll
      for (int c = 0; c < 16; ++c) acc[c] = fmaf(xv[m], w[m][c], acc[c]);
    }

    {
      const bool hi = (lane & 1) != 0;
      #pragma unroll
      for (int v = 0; v < 8; ++v) {
        float send = hi ? acc[v] : acc[v + 8];
        float rcv = __shfl_xor(send, 1);
        acc[v] = (hi ? acc[v + 8] : acc[v]) + rcv;
      }
    }
    {
      const bool hi = (lane & 2) != 0;
      #pragma unroll
      for (int v = 0; v < 4; ++v) {
        float send = hi ? acc[v] : acc[v + 4];
        float rcv = __shfl_xor(send, 2);
        acc[v] = (hi ? acc[v + 4] : acc[v]) + rcv;
      }
    }
    {
      const bool hi = (lane & 4) != 0;
      #pragma unroll
      for (int v = 0; v < 2; ++v) {
        float send = hi ? acc[v] : acc[v + 2];
        float rcv = __shfl_xor(send, 4);
        acc[v] = (hi ? acc[v + 2] : acc[v]) + rcv;
      }
    }
    {
      const bool hi = (lane & 8) != 0;
      float send = hi ? acc[0] : acc[1];
      float rcv = __shfl_xor(send, 8);
      acc[0] = (hi ? acc[1] : acc[0]) + rcv;
    }
    float vsum = acc[0];
    vsum += __shfl_xor(vsum, 16);
    vsum += __shfl_xor(vsum, 32);

    if (lane < 16) hs[(size_t)i * 16 + c_out] = dis[i] * vsum;

    a = an; b = bn; i = inext;
  }
}

// ------- layer 1 aggregate + self-loop + ELU + layer-2 prescale ------
// wave-per-node, float4 gather: c4=lane&3 (quarter-row), r=lane>>2 (16
// edge slots in flight). csr prefetch overlaps index load with gather.
__global__ __launch_bounds__(256) void k_agg1(
    const int* __restrict__ offs, const int* __restrict__ csr,
    const float* __restrict__ hs, const float* __restrict__ dis,
    const float* __restrict__ b1, float* __restrict__ h1s, int n) {
  int wave = blockIdx.x * 4 + (threadIdx.x >> 6);
  if (wave >= n) return;
  int lane = threadIdx.x & 63;
  int c4 = lane & 3, r = lane >> 2;
  int beg = offs[wave], end = offs[wave + 1];
  const float4* hs4 = reinterpret_cast<const float4*>(hs);

  float ax = 0.f, ay = 0.f, az = 0.f, aw = 0.f;
  int k = beg + r;
  int s = (k < end) ? csr[k] : 0;
  while (k < end) {
    int k2 = k + 16;
    int s2 = (k2 < end) ? csr[k2] : 0;
    float4 v = hs4[(size_t)s * 4 + c4];
    ax += v.x; ay += v.y; az += v.z; aw += v.w;
    s = s2; k = k2;
  }
  #pragma unroll
  for (int m = 4; m <= 32; m <<= 1) {
    ax += __shfl_xor(ax, m); ay += __shfl_xor(ay, m);
    az += __shfl_xor(az, m); aw += __shfl_xor(aw, m);
  }
  // self loop + scale + bias + elu
  float4 sf = hs4[(size_t)wave * 4 + c4];
  float di = dis[wave];
  float4 b1v = reinterpret_cast<const float4*>(b1)[c4];
  float ox = fmaf(di, ax + sf.x, b1v.x);
  float oy = fmaf(di, ay + sf.y, b1v.y);
  float oz = fmaf(di, az + sf.z, b1v.z);
  float ow = fmaf(di, aw + sf.w, b1v.w);
  float4 o;
  o.x = di * (ox > 0.f ? ox : expm1f(ox));
  o.y = di * (oy > 0.f ? oy : expm1f(oy));
  o.z = di * (oz > 0.f ? oz : expm1f(oz));
  o.w = di * (ow > 0.f ? ow : expm1f(ow));
  if (r == 0) reinterpret_cast<float4*>(h1s)[(size_t)wave * 4 + c4] = o;
}

// ------- layer 2 aggregate + 16x16 matvec + bias + log_softmax -------
__global__ __launch_bounds__(256) void k_agg2(
    const int* __restrict__ offs, const int* __restrict__ csr,
    const float* __restrict__ h1s, const float* __restrict__ dis,
    const float* __restrict__ W2, const float* __restrict__ b2,
    float* __restrict__ out, int n) {
  __shared__ float w2s[256];
  w2s[threadIdx.x] = W2[threadIdx.x];
  __syncthreads();
  int wave = blockIdx.x * 4 + (threadIdx.x >> 6);
  if (wave >= n) return;
  int lane = threadIdx.x & 63;
  int c4 = lane & 3, r = lane >> 2;
  int beg = offs[wave], end = offs[wave + 1];
  const float4* h4 = reinterpret_cast<const float4*>(h1s);

  float ax = 0.f, ay = 0.f, az = 0.f, aw = 0.f;
  int k = beg + r;
  int s = (k < end) ? csr[k] : 0;
  while (k < end) {
    int k2 = k + 16;
    int s2 = (k2 < end) ? csr[k2] : 0;
    float4 v = h4[(size_t)s * 4 + c4];
    ax += v.x; ay += v.y; az += v.z; aw += v.w;
    s = s2; k = k2;
  }
  #pragma unroll
  for (int m = 4; m <= 32; m <<= 1) {
    ax += __shfl_xor(ax, m); ay += __shfl_xor(ay, m);
    az += __shfl_xor(az, m); aw += __shfl_xor(aw, m);
  }
  // self loop + dst-side scale: every lane now holds final scaled agg
  // for its 4 features [c4*4, c4*4+4)
  float4 sf = h4[(size_t)wave * 4 + c4];
  float di = dis[wave];
  float sx = di * (ax + sf.x);
  float sy = di * (ay + sf.y);
  float sz = di * (az + sf.z);
  float sw = di * (aw + sf.w);
  // redistribute: lane computes out column c = lane&15
  int c = lane & 15;
  int lbase = lane & ~3;
  float dot = 0.f;
  #pragma unroll
  for (int k16 = 0; k16 < 16; ++k16) {
    int srcl = lbase | (k16 >> 2);
    float comp = (k16 & 3) == 0 ? sx : (k16 & 3) == 1 ? sy : (k16 & 3) == 2 ? sz : sw;
    float vk = __shfl(comp, srcl);
    dot = fmaf(vk, w2s[k16 * 16 + c], dot);
  }
  float o = dot + b2[c];
  // log_softmax over the 16-lane class group
  float m = o;
  m = fmaxf(m, __shfl_xor(m, 1));
  m = fmaxf(m, __shfl_xor(m, 2));
  m = fmaxf(m, __shfl_xor(m, 4));
  m = fmaxf(m, __shfl_xor(m, 8));
  float ex = expf(o - m);
  float ssum = ex;
  ssum += __shfl_xor(ssum, 1);
  ssum += __shfl_xor(ssum, 2);
  ssum += __shfl_xor(ssum, 4);
  ssum += __shfl_xor(ssum, 8);
  if (lane < 16) out[(size_t)wave * 16 + c] = o - m - logf(ssum);
}

// ---------------- launch ----------------
extern "C" void kernel_launch(void* const* d_in, const int* in_sizes, int n_in,
                              void* d_out, int out_size, void* d_ws, size_t ws_size,
                              hipStream_t stream) {
  const float* x  = (const float*)d_in[0];
  const int*   ei = (const int*)d_in[1];
  const float* W1 = (const float*)d_in[2];
  const float* b1 = (const float*)d_in[3];
  const float* W2 = (const float*)d_in[4];
  const float* b2 = (const float*)d_in[5];
  float* out = (float*)d_out;

  const int n = in_sizes[0] / 512;
  const int E = in_sizes[1] / 2;
  const int* src = ei;
  const int* dst = ei + E;

  const int NB = (n + BKT_SZ - 1) >> BKT_SHIFT;       // 391 buckets
  const int NCHUNK = (E + CHUNK - 1) / CHUNK;         // 391 chunks
  const int total = NB * NCHUNK;                      // 152881
  const int sb = (total + TPB - 1) / TPB;             // 598 scan blocks

  char* ws = (char*)d_ws;
  size_t off = 0;
  auto alloc = [&](size_t bytes) -> void* {
    void* p = (void*)(ws + off);
    off += (bytes + 255) & ~(size_t)255;
    return p;
  };
  int*          counts = (int*)alloc((size_t)total * 4);
  int*          btot   = (int*)alloc(1024 * 4);
  unsigned int* part   = (unsigned int*)alloc((size_t)E * 4);
  int*          offs   = (int*)alloc((size_t)(n + 1) * 4);
  int*          csr    = (int*)alloc((size_t)E * 4);
  float*        dis    = (float*)alloc((size_t)n * 4);
  float*        hs     = (float*)alloc((size_t)n * 16 * 4);
  float*        h1s    = (float*)alloc((size_t)n * 16 * 4);
  (void)ws_size; (void)n_in; (void)out_size;

  const int ab = (n + 3) / 4;                         // 4 nodes per block

  k_count<<<NCHUNK, TPB, 0, stream>>>(dst, counts, E, NB, NCHUNK);
  k_scan1<<<sb, TPB, 0, stream>>>(counts, btot, total);
  k_scan2<<<1, 1024, 0, stream>>>(btot, sb);
  k_part <<<NCHUNK, TPB, 0, stream>>>(src, dst, counts, btot, part, E, NB, NCHUNK);
  k_build<<<NB, TPB, 0, stream>>>(part, counts, btot, offs, csr, dis, n, E, NB, NCHUNK);
  k_gemm1<<<2048, TPB, 0, stream>>>(x, W1, dis, hs, n, 2048 * 4);
  k_agg1 <<<ab, TPB, 0, stream>>>(offs, csr, hs, dis, b1, h1s, n);
  k_agg2 <<<ab, TPB, 0, stream>>>(offs, csr, h1s, dis, W2, b2, out, n);
}